// Round 1
// baseline (5069.178 us; speedup 1.0000x reference)
//
#include <hip/hip_runtime.h>
#include <hip/hip_bf16.h>
#include <hip/hip_fp16.h>

// Problem constants
#define NB   1024           // batch N
#define HD   1024           // hidden H
#define LSTEPS 96           // L
#define M4   4096           // 4*H (gate rows)
#define KKDIM 1024          // K = H
#define BN_EPS 1e-5f

typedef _Float16 f16;
typedef _Float16 f16x8 __attribute__((ext_vector_type(8)));
typedef float f32x4 __attribute__((ext_vector_type(4)));

// Workspace layout (bytes):
//   Wb   f16 [4096][1024]   8,388,608  @ 0
//   hA   f16 [1024][1024]   2,097,152  @ 8,388,608
//   hB   f16 [1024][1024]   2,097,152  @ 10,485,760
//   c    f32 [1024][1024]   4,194,304  @ 12,582,912
//   bsum f32 [4096]            16,384  @ 16,777,216
//   G    f32 [1024][4096]  16,777,216  @ 16,793,600
//   stat f32 [1024][2]          8,192  @ 33,570,816
// total ~33.6 MB

#define GLOAD_LDS16(gp, lp) __builtin_amdgcn_global_load_lds( \
    (const __attribute__((address_space(1))) void*)(gp),      \
    (__attribute__((address_space(3))) void*)(lp), 16, 0, 0)

// ---------------------------------------------------------------------------
// prep: W fp32->f16, h_in fp32->f16, c=0, bias = b_ih + b_hh
__global__ __launch_bounds__(256) void prep_kernel(
    const float* __restrict__ W, const float* __restrict__ hin,
    const float* __restrict__ bih, const float* __restrict__ bhh,
    f16* __restrict__ Wb, f16* __restrict__ hA, float* __restrict__ c,
    float* __restrict__ bsum) {
  int i = blockIdx.x * 256 + threadIdx.x;
  int stride = gridDim.x * 256;
  for (int idx = i; idx < M4 * KKDIM; idx += stride) Wb[idx] = (f16)W[idx];
  for (int idx = i; idx < NB * HD; idx += stride) { hA[idx] = (f16)hin[idx]; c[idx] = 0.f; }
  for (int idx = i; idx < M4; idx += stride) bsum[idx] = bih[idx] + bhh[idx];
}

// ---------------------------------------------------------------------------
// GEMM: G[n][m] = sum_k h[n][k] * W[m][k] + bias[m]
// A = h (1024 x 1024, f16 row-major), BT = Wb (4096 x 1024, f16 row-major)
// 128x128 tile, BK=64, 4 waves (2x2), 4x4 fragments of 16x16x32 MFMA.
__global__ __launch_bounds__(256) void gemm_step(
    const f16* __restrict__ A, const f16* __restrict__ BT,
    const float* __restrict__ bias, float* __restrict__ G) {
  __shared__ f16 As[128 * 64];
  __shared__ f16 Bs[128 * 64];
  const int tid  = threadIdx.x;
  const int lane = tid & 63;
  const int wv   = tid >> 6;
  const int wrow = wv >> 1, wcol = wv & 1;
  const int tm = (blockIdx.x & 7) * 128;    // 8 row tiles over N=1024
  const int tn = (blockIdx.x >> 3) * 128;   // 32 col tiles over 4096

  f32x4 acc[4][4] = {};

  for (int kt = 0; kt < KKDIM / 64; ++kt) {
    __syncthreads();
#pragma unroll
    for (int r = 0; r < 4; ++r) {
      int idx = r * 256 + tid;
      int row = idx >> 3;
      int c8  = (idx & 7) << 3;
      GLOAD_LDS16(A  + (size_t)(tm + row) * KKDIM + kt * 64 + c8, &As[idx * 8]);
      GLOAD_LDS16(BT + (size_t)(tn + row) * KKDIM + kt * 64 + c8, &Bs[idx * 8]);
    }
    __syncthreads();
#pragma unroll
    for (int kk = 0; kk < 2; ++kk) {
      f16x8 af[4], bfr[4];
#pragma unroll
      for (int mi = 0; mi < 4; ++mi) {
        int row = wrow * 64 + mi * 16 + (lane & 15);
        af[mi] = *(const f16x8*)&As[row * 64 + kk * 32 + (lane >> 4) * 8];
      }
#pragma unroll
      for (int ni = 0; ni < 4; ++ni) {
        int col = wcol * 64 + ni * 16 + (lane & 15);
        bfr[ni] = *(const f16x8*)&Bs[col * 64 + kk * 32 + (lane >> 4) * 8];
      }
#pragma unroll
      for (int mi = 0; mi < 4; ++mi)
#pragma unroll
        for (int ni = 0; ni < 4; ++ni)
          acc[mi][ni] = __builtin_amdgcn_mfma_f32_16x16x32_f16(
              af[mi], bfr[ni], acc[mi][ni], 0, 0, 0);
    }
  }

  // epilogue: C/D layout col = lane&15, row = (lane>>4)*4 + q  [m89/m91]
#pragma unroll
  for (int mi = 0; mi < 4; ++mi) {
    int nrow = tm + wrow * 64 + mi * 16 + (lane >> 4) * 4;
#pragma unroll
    for (int ni = 0; ni < 4; ++ni) {
      int mcol = tn + wcol * 64 + ni * 16 + (lane & 15);
      float bb = bias[mcol];
#pragma unroll
      for (int q = 0; q < 4; ++q)
        G[(size_t)(nrow + q) * M4 + mcol] = acc[mi][ni][q] + bb;
    }
  }
}

// ---------------------------------------------------------------------------
// LSTM elementwise: gates (i,f,g,o) -> c,h ; write h to next-step f16 buffer
// and to d_out[n][j][l] (fp32).
__global__ __launch_bounds__(256) void lstm_elem(
    const float* __restrict__ G, float* __restrict__ c,
    f16* __restrict__ hnext, float* __restrict__ out, int l) {
  int idx = blockIdx.x * 256 + threadIdx.x;   // 1M threads
  int n = idx >> 10, j = idx & 1023;
  const float* g = G + (size_t)n * M4;
  float xi = g[j], xf = g[j + 1024], xg = g[j + 2048], xo = g[j + 3072];
  float si = 1.f / (1.f + __expf(-xi));
  float sf = 1.f / (1.f + __expf(-xf));
  float tg = tanhf(xg);
  float so = 1.f / (1.f + __expf(-xo));
  float cn = sf * c[idx] + si * tg;
  float h  = so * tanhf(cn);
  c[idx] = cn;
  hnext[idx] = (f16)h;
  out[(size_t)n * (HD * LSTEPS) + (size_t)j * LSTEPS + l] = h;
}

// ---------------------------------------------------------------------------
// BatchNorm stats: one block per channel j; reduce over (n,l) = 98304 elems.
__global__ __launch_bounds__(256) void bn_stats(
    const float* __restrict__ out, const float* __restrict__ gamma,
    const float* __restrict__ beta, float* __restrict__ stat) {
  int j = blockIdx.x;
  float s = 0.f, s2 = 0.f;
  for (int t = threadIdx.x; t < NB * LSTEPS; t += 256) {
    int n = t / LSTEPS, l = t - n * LSTEPS;
    float v = out[(size_t)n * (HD * LSTEPS) + (size_t)j * LSTEPS + l];
    s += v; s2 += v * v;
  }
#pragma unroll
  for (int off = 32; off; off >>= 1) {
    s  += __shfl_down(s, off);
    s2 += __shfl_down(s2, off);
  }
  __shared__ float rs[4], rs2[4];
  int lane = threadIdx.x & 63, w = threadIdx.x >> 6;
  if (lane == 0) { rs[w] = s; rs2[w] = s2; }
  __syncthreads();
  if (threadIdx.x == 0) {
    float S  = rs[0] + rs[1] + rs[2] + rs[3];
    float S2 = rs2[0] + rs2[1] + rs2[2] + rs2[3];
    const float inv = 1.f / (float)(NB * LSTEPS);
    float mean = S * inv;
    float var  = S2 * inv - mean * mean;
    float sc = gamma[j] * rsqrtf(var + BN_EPS);
    stat[2 * j]     = sc;
    stat[2 * j + 1] = beta[j] - mean * sc;
  }
}

// normalize in place, float4 vectorized. 96 floats per (n,j) row = 24 float4.
__global__ __launch_bounds__(256) void bn_apply(
    float* __restrict__ out, const float* __restrict__ stat) {
  size_t i4 = (size_t)blockIdx.x * 256 + threadIdx.x;  // 25,165,824 total
  float4 v = ((const float4*)out)[i4];
  int j = (int)((i4 / 24) & 1023);
  float sc = stat[2 * j], sh = stat[2 * j + 1];
  v.x = v.x * sc + sh; v.y = v.y * sc + sh;
  v.z = v.z * sc + sh; v.w = v.w * sc + sh;
  ((float4*)out)[i4] = v;
}

// ---------------------------------------------------------------------------
extern "C" void kernel_launch(void* const* d_in, const int* in_sizes, int n_in,
                              void* d_out, int out_size, void* d_ws, size_t ws_size,
                              hipStream_t stream) {
  const float* h_in  = (const float*)d_in[0];
  const float* W     = (const float*)d_in[1];
  const float* bih   = (const float*)d_in[2];
  const float* bhh   = (const float*)d_in[3];
  const float* gamma = (const float*)d_in[4];
  const float* beta  = (const float*)d_in[5];
  float* out = (float*)d_out;

  char* ws = (char*)d_ws;
  f16*   Wb   = (f16*)(ws + 0);
  f16*   hA   = (f16*)(ws + 8388608);
  f16*   hB   = (f16*)(ws + 10485760);
  float* c    = (float*)(ws + 12582912);
  float* bsum = (float*)(ws + 16777216);
  float* G    = (float*)(ws + 16793600);
  float* stat = (float*)(ws + 33570816);

  prep_kernel<<<4096, 256, 0, stream>>>(W, h_in, bih, bhh, Wb, hA, c, bsum);

  f16* hc = hA;
  f16* hx = hB;
  for (int l = 0; l < LSTEPS; ++l) {
    gemm_step<<<256, 256, 0, stream>>>(hc, Wb, bsum, G);
    lstm_elem<<<4096, 256, 0, stream>>>(G, c, hx, out, l);
    f16* t = hc; hc = hx; hx = t;
  }

  bn_stats<<<1024, 256, 0, stream>>>(out, gamma, beta, stat);
  bn_apply<<<98304, 256, 0, stream>>>(out, stat);
}

// Round 2
// 2886.892 us; speedup vs baseline: 1.7559x; 1.7559x over previous
//
#include <hip/hip_runtime.h>
#include <hip/hip_fp16.h>

// Problem: N=1024 batch, H=1024 hidden, L=96 steps, gates 4H=4096, K=H=1024.
#define LSTEPS 96
#define BN_EPS 1e-5f

typedef _Float16 f16;
typedef _Float16 f16x8 __attribute__((ext_vector_type(8)));
typedef float f32x4 __attribute__((ext_vector_type(4)));
typedef float f32x16 __attribute__((ext_vector_type(16)));

#define GLOAD_LDS16(gp, lp) __builtin_amdgcn_global_load_lds( \
    (const __attribute__((address_space(1))) void*)(gp),      \
    (__attribute__((address_space(3))) void*)(lp), 16, 0, 0)

__device__ __forceinline__ float sigf(float x) { return 1.f / (1.f + __expf(-x)); }
__device__ __forceinline__ float tanhfast(float x) {
  float e = __expf(2.f * x);
  return 1.f - 2.f / (e + 1.f);   // exact at +-inf overflow: ->1 / ->-1
}

// ---------------------------------------------------------------------------
// Fragment-ordered global layouts (for mfma_f32_32x32x16_f16):
//   A (h, 1024x1024):  frag(r32,k16) id = r32*64 + k16 ; within frag:
//     lane = (row&31) | (((k>>3)&1)<<5), elems e = k&7 ; 512 f16 = 1KB.
//   W' (4096x1024 gate-interleaved): col' = cb*128 + g*32 + j  (cb=0..31
//     channel-block, g=gate, j=channel-in-block); frag(col32,k16),
//     col32 = cb*4+g; same lane rule with col in place of row.
// ---------------------------------------------------------------------------
__global__ __launch_bounds__(256) void prep_kernel(
    const float* __restrict__ W, const float* __restrict__ hin,
    const float* __restrict__ bih, const float* __restrict__ bhh,
    f16* __restrict__ Wfrag, f16* __restrict__ Afrag, float* __restrict__ c,
    float* __restrict__ bias, float* __restrict__ ssum, float* __restrict__ ssq) {
  const int t0 = blockIdx.x * 256 + threadIdx.x;
  const int stride = gridDim.x * 256;
  // W -> f16 fragment order: 4M elems = 524288 chunks of 8
  for (int t = t0; t < 524288; t += stride) {
    int lane = t & 63, frag = t >> 6;
    int col32 = frag >> 6, k16 = frag & 63;
    int g = col32 & 3, cb = col32 >> 2;
    int m = g * 1024 + cb * 32 + (lane & 31);
    int k0 = k16 * 16 + (lane >> 5) * 8;
    const float* src = W + (size_t)m * 1024 + k0;
    f16x8 v;
#pragma unroll
    for (int e = 0; e < 8; ++e) v[e] = (f16)src[e];
    *(f16x8*)(Wfrag + (size_t)t * 8) = v;
  }
  // h0 -> f16 fragment order: 131072 chunks
  for (int t = t0; t < 131072; t += stride) {
    int lane = t & 63, frag = t >> 6;
    int r32 = frag >> 6, k16 = frag & 63;
    int row = r32 * 32 + (lane & 31);
    int k0 = k16 * 16 + (lane >> 5) * 8;
    const float* src = hin + (size_t)row * 1024 + k0;
    f16x8 v;
#pragma unroll
    for (int e = 0; e < 8; ++e) v[e] = (f16)src[e];
    *(f16x8*)(Afrag + (size_t)t * 8) = v;
  }
  for (int t = t0; t < 1048576; t += stride) c[t] = 0.f;
  for (int t = t0; t < 4096; t += stride) {
    int g = (t >> 5) & 3, cb = t >> 7, j = t & 31;
    int m = g * 1024 + cb * 32 + j;
    bias[t] = bih[m] + bhh[m];
  }
  for (int t = t0; t < 1024; t += stride) { ssum[t] = 0.f; ssq[t] = 0.f; }
}

// ---------------------------------------------------------------------------
// Fused step: gates = h @ W'^T + bias ; c,h update ; h out to stage (f32,
// [n][j] coalesced) and to Anext (f16, fragment order, via LDS shuffle).
// Grid 256 = 8 bg x 32 cb, XCD-mapped: bid&7 -> XCD, each XCD sees 4 cb
// (W working set 1MB, L2-resident). Block tile: 128 batch x 128 cols
// (= 32 channels x 4 gates). 4 waves, each 32 batch rows x all 128 cols.
__global__ __launch_bounds__(256) void step_kernel(
    const f16* __restrict__ Acur, const f16* __restrict__ Wfrag,
    const float* __restrict__ bias, float* __restrict__ c,
    f16* __restrict__ Anext, float* __restrict__ stage, int lmod) {
  __shared__ alignas(16) f16 As[2 * 16 * 512];   // [buf][r32(4)][k16(4)][512]
  __shared__ alignas(16) f16 Bs[2 * 16 * 512];   // [buf][g(4)][k16(4)][512]
  __shared__ alignas(16) f16 hl[128 * 40];       // h tile, padded to 40 f16/row
  const int tid = threadIdx.x, lane = tid & 63, wv = tid >> 6;
  const int bid = blockIdx.x;
  const int cb = (bid & 7) * 4 + ((bid >> 3) & 3);
  const int bg = bid >> 5;

  const f16* Ag = Acur + (size_t)(bg * 4) * 64 * 512 + lane * 8;
  const f16* Wg = Wfrag + (size_t)(cb * 4) * 64 * 512 + lane * 8;

  f32x16 acc[4] = {};   // one accumulator per gate (i,f,g,o)

#define STAGE(B, KT)                                                   \
  {                                                                    \
    _Pragma("unroll")                                                  \
    for (int r = 0; r < 4; ++r) {                                      \
      GLOAD_LDS16(Ag + ((size_t)r * 64 + (KT) * 4 + wv) * 512,         \
                  &As[((B) * 16 + r * 4 + wv) * 512 + lane * 8]);      \
      GLOAD_LDS16(Wg + ((size_t)r * 64 + (KT) * 4 + wv) * 512,         \
                  &Bs[((B) * 16 + r * 4 + wv) * 512 + lane * 8]);      \
    }                                                                  \
  }

  STAGE(0, 0);
  __syncthreads();
  int buf = 0;
  for (int kt = 0; kt < 16; ++kt) {
    if (kt < 15) STAGE(buf ^ 1, kt + 1);   // loads fly across compute phase
#pragma unroll
    for (int kk = 0; kk < 4; ++kk) {
      f16x8 a = *(const f16x8*)&As[(buf * 16 + wv * 4 + kk) * 512 + lane * 8];
#pragma unroll
      for (int g = 0; g < 4; ++g) {
        f16x8 b = *(const f16x8*)&Bs[(buf * 16 + g * 4 + kk) * 512 + lane * 8];
        acc[g] = __builtin_amdgcn_mfma_f32_32x32x16_f16(a, b, acc[g], 0, 0, 0);
      }
    }
    __syncthreads();   // drains vmcnt (stage) + lgkm; swap buffers
    buf ^= 1;
  }

  // ---- epilogue: C/D layout col=lane&31, row=(reg&3)+8*(reg>>2)+4*(lane>>5)
  const int jl = lane & 31;
  float bi[4];
#pragma unroll
  for (int g = 0; g < 4; ++g) bi[g] = bias[cb * 128 + g * 32 + jl];

  float* cp = c + ((size_t)bid * 256 + tid) * 16;   // per-thread coalesced c
  f32x4 cv[4];
#pragma unroll
  for (int q = 0; q < 4; ++q) cv[q] = ((const f32x4*)cp)[q];

  float hv[16];
#pragma unroll
  for (int reg = 0; reg < 16; ++reg) {
    float xi = acc[0][reg] + bi[0];
    float xf = acc[1][reg] + bi[1];
    float xg = acc[2][reg] + bi[2];
    float xo = acc[3][reg] + bi[3];
    float cold = cv[reg >> 2][reg & 3];
    float cn = sigf(xf) * cold + sigf(xi) * tanhfast(xg);
    cv[reg >> 2][reg & 3] = cn;
    hv[reg] = sigf(xo) * tanhfast(cn);
  }
#pragma unroll
  for (int q = 0; q < 4; ++q) ((f32x4*)cp)[q] = cv[q];

  float* stp = stage + (size_t)lmod * 1048576 + (size_t)(bg * 128) * 1024 + cb * 32 + jl;
  const int rl4 = 4 * (lane >> 5);
#pragma unroll
  for (int reg = 0; reg < 16; ++reg) {
    int row_local = (reg & 3) + 8 * (reg >> 2) + rl4;        // 0..31 in wave
    stp[(size_t)(wv * 32 + row_local) * 1024] = hv[reg];     // coalesced f32
    hl[(wv * 32 + row_local) * 40 + jl] = (f16)hv[reg];
  }
  __syncthreads();
  // emit h in fragment order for next step's A (wave reads only its own rows)
  {
    const int row_l = lane & 31, e0 = (lane >> 5) * 8;
#pragma unroll
    for (int kh = 0; kh < 2; ++kh) {
      f16x8 v = *(const f16x8*)&hl[(wv * 32 + row_l) * 40 + kh * 16 + e0];
      size_t fg = (size_t)((bg * 4 + wv) * 64 + cb * 2 + kh);
      *(f16x8*)(Anext + fg * 512 + lane * 8) = v;
    }
  }
#undef STAGE
}

// ---------------------------------------------------------------------------
// Transpose 16 staged steps into out[n][j][l0..l0+15] + BN partial sums.
// Grid 256 = 64 n-chunks x 4 j-chunks; thread owns one j, 16 n, 16 l.
__global__ __launch_bounds__(256) void transpose_kernel(
    const float* __restrict__ stage, float* __restrict__ out,
    float* __restrict__ ssum, float* __restrict__ ssq, int l0) {
  const int j = (blockIdx.x & 3) * 256 + threadIdx.x;
  const int n0 = (blockIdx.x >> 2) * 16;
  float s = 0.f, s2 = 0.f;
  for (int ni = 0; ni < 16; ++ni) {
    const int n = n0 + ni;
    const float* sp = stage + (size_t)n * 1024 + j;
    float v[16];
#pragma unroll
    for (int l = 0; l < 16; ++l) {
      v[l] = sp[(size_t)l * 1048576];
      s += v[l];
      s2 += v[l] * v[l];
    }
    float* op = out + ((size_t)n * 1024 + j) * 96 + l0;
#pragma unroll
    for (int q = 0; q < 4; ++q)
      ((f32x4*)op)[q] = (f32x4){v[4*q], v[4*q+1], v[4*q+2], v[4*q+3]};
  }
  atomicAdd(&ssum[j], s);
  atomicAdd(&ssq[j], s2);
}

__global__ __launch_bounds__(256) void bn_scale_kernel(
    const float* __restrict__ ssum, const float* __restrict__ ssq,
    const float* __restrict__ gamma, const float* __restrict__ beta,
    float* __restrict__ stat2) {
  int j = blockIdx.x * 256 + threadIdx.x;
  const float inv = 1.f / 98304.f;   // N*L
  float mean = ssum[j] * inv;
  float var = ssq[j] * inv - mean * mean;
  float sc = gamma[j] * rsqrtf(var + BN_EPS);
  stat2[2 * j] = sc;
  stat2[2 * j + 1] = beta[j] - mean * sc;
}

__global__ __launch_bounds__(256) void bn_apply(
    float* __restrict__ out, const float* __restrict__ stat2) {
  size_t i4 = (size_t)blockIdx.x * 256 + threadIdx.x;   // 25,165,824 float4s
  f32x4 v = ((const f32x4*)out)[i4];
  int j = (int)((i4 / 24) & 1023);
  float sc = stat2[2 * j], sh = stat2[2 * j + 1];
  v[0] = v[0] * sc + sh; v[1] = v[1] * sc + sh;
  v[2] = v[2] * sc + sh; v[3] = v[3] * sc + sh;
  ((f32x4*)out)[i4] = v;
}

// ---------------------------------------------------------------------------
// ws layout (bytes):
//   Wfrag  f16  8,388,608 @ 0
//   Afrag0 f16  2,097,152 @  8,388,608
//   Afrag1 f16  2,097,152 @ 10,485,760
//   c      f32  4,194,304 @ 12,582,912
//   bias   f32     16,384 @ 16,777,216
//   ssum   f32      4,096 @ 16,793,600
//   ssq    f32      4,096 @ 16,797,696
//   stat2  f32      8,192 @ 16,801,792
//   stage  f32 67,108,864 @ 16,809,984   (16 slots of [1024][1024])
// total ~84 MB
extern "C" void kernel_launch(void* const* d_in, const int* in_sizes, int n_in,
                              void* d_out, int out_size, void* d_ws, size_t ws_size,
                              hipStream_t stream) {
  const float* h_in  = (const float*)d_in[0];
  const float* W     = (const float*)d_in[1];
  const float* bih   = (const float*)d_in[2];
  const float* bhh   = (const float*)d_in[3];
  const float* gamma = (const float*)d_in[4];
  const float* beta  = (const float*)d_in[5];
  float* out = (float*)d_out;

  char* ws = (char*)d_ws;
  f16*   Wfrag = (f16*)(ws + 0);
  f16*   Af0   = (f16*)(ws + 8388608);
  f16*   Af1   = (f16*)(ws + 10485760);
  float* c     = (float*)(ws + 12582912);
  float* bias  = (float*)(ws + 16777216);
  float* ssum  = (float*)(ws + 16793600);
  float* ssq   = (float*)(ws + 16797696);
  float* stat2 = (float*)(ws + 16801792);
  float* stage = (float*)(ws + 16809984);

  prep_kernel<<<1024, 256, 0, stream>>>(W, h_in, bih, bhh, Wfrag, Af0, c,
                                        bias, ssum, ssq);

  f16* a = Af0;
  f16* b = Af1;
  for (int l = 0; l < LSTEPS; ++l) {
    step_kernel<<<256, 256, 0, stream>>>(a, Wfrag, bias, c, b, stage, l & 15);
    f16* t = a; a = b; b = t;
    if ((l & 15) == 15)
      transpose_kernel<<<256, 256, 0, stream>>>(stage, out, ssum, ssq, l - 15);
  }

  bn_scale_kernel<<<4, 256, 0, stream>>>(ssum, ssq, gamma, beta, stat2);
  bn_apply<<<98304, 256, 0, stream>>>(out, stat2);
}